// Round 7
// baseline (126.640 us; speedup 1.0000x reference)
//
#include <hip/hip_runtime.h>
#include <math.h>

// DSVF via exact time-domain IIR (== reference's FFT overlap-add: pole
// radius r <= 0.55 robustly; warm-up truncation 0.55^32 ~ 5e-9 relative,
// ~1e-7 absolute vs 1.6e-2 tolerance).
//
// R11 = R9 restored (nt stores back: R10's plain-store isolation REGRESSED
// +4.1 us -> nt stores are a real ~4 us win; cache policy, not scheduling,
// is the live lever) + nt LOADS: input is also touched exactly once, so
// keep the 67 MB read stream out of L2 allocation too. Full streaming
// policy on both sides = the configuration the pure-stream fills (6.4
// TB/s) actually run in.
//
// Structure (R9): 2048 blocks = 8/CU, 2 tiles/block, tile t+1 loads issued
// before tile t compute, wave-private swizzled b128 LDS, zero barriers.

#define N_PER_ROW (128 * 2048)     // 262144 samples per row
#define BATCH 64
#define TPB 256
#define OUT_BLK 16                 // outputs per thread
#define WARM 32                    // warm-up samples per thread
#define WTILE (64 * OUT_BLK)       // 1024 outputs per wave
#define TILE (TPB * OUT_BLK)       // 4096 outputs per block-tile
#define TILES_PER_ROW (N_PER_ROW / TILE)     // 64
#define TILES_PER_BLK 2
#define BLKS_PER_ROW (TILES_PER_ROW / TILES_PER_BLK)  // 32
#define WCHUNKS ((WARM + WTILE) / 4)         // 264 16-B chunks per wave

typedef float vfloat4 __attribute__((ext_vector_type(4)));

#define NTLOAD(addr) __builtin_nontemporal_load((const vfloat4*)(addr))

// Involution on chunk index: XOR low 3 bits with the next 3 bits.
// Every access phase lands 8 lanes per 4-bank group: conflict-free b128.
__device__ __forceinline__ int swz(int c) { return c ^ ((c >> 3) & 7); }

__global__ __launch_bounds__(256, 8) void dsvf_iir_kernel(
    const float* __restrict__ x,
    const float* __restrict__ g_p, const float* __restrict__ R_p,
    const float* __restrict__ mhp_p, const float* __restrict__ mbp_p,
    const float* __restrict__ mlp_p,
    float* __restrict__ out)
{
    __shared__ vfloat4 lds[4 * WCHUNKS];     // 4 wave-private regions, 16.9 KB

    const int p    = blockIdx.x;
    const int row  = p >> 5;                 // / BLKS_PER_ROW (=32)
    const int tl0  = (p & (BLKS_PER_ROW - 1)) * TILES_PER_BLK;
    const int k    = threadIdx.x;
    const int wid  = k >> 6;                 // wave 0..3
    const int lane = k & 63;

    const size_t base0 = (size_t)row * N_PER_ROW + (size_t)tl0 * TILE
                       + (size_t)wid * WTILE;
    const float* __restrict__ src0 = x + base0;
    const float* __restrict__ src1 = src0 + TILE;   // same wave slot, next tile
    vfloat4* const wlds = &lds[wid * WCHUNKS];

    // --- tile0 loads (registers, streaming: input is touched once) ---
    vfloat4 a0 = NTLOAD(src0 +   0 + 4 * lane);
    vfloat4 a1 = NTLOAD(src0 + 256 + 4 * lane);
    vfloat4 a2 = NTLOAD(src0 + 512 + 4 * lane);
    vfloat4 a3 = NTLOAD(src0 + 768 + 4 * lane);
    vfloat4 ah;
    if (lane < 8) {
        if (tl0 == 0 && wid == 0) { ah = (vfloat4){0.f, 0.f, 0.f, 0.f}; }
        else                      { ah = NTLOAD(src0 - WARM + 4 * lane); }
    }

    // --- biquad coefficients (identical math to reference, fp32) ---
    const float g = g_p[0], R = R_p[0];
    const float m_hp = mhp_p[0], m_bp = mbp_p[0], m_lp = mlp_p[0];
    const float sig = 1.0f / (1.0f + expf(-g));
    const float gt  = tanf(1.5707963267948966f * sig);   // tan(pi*sig/2)
    const float Rt  = log1pf(expf(R));                   // softplus
    const float g2  = gt * gt;
    const float b0 = g2 * m_lp + gt * m_bp + m_hp;
    const float b1 = 2.0f * g2 * m_lp - 2.0f * m_hp;
    const float b2 = g2 * m_lp - gt * m_bp + m_hp;
    const float a0c = g2 + 2.0f * Rt * gt + 1.0f;
    const float a1c = 2.0f * g2 - 2.0f;
    const float a2c = g2 - 2.0f * Rt * gt + 1.0f;
    const float inv_a0 = 1.0f / a0c;
    const float B0 = b0 * inv_a0, B1 = b1 * inv_a0, B2 = b2 * inv_a0;
    const float A1 = a1c * inv_a0, A2 = a2c * inv_a0;

#define STEP_D(xx) { float y_ = fmaf(B0, (xx), s1);                 \
                     s1 = fmaf(-A1, y_, fmaf(B1, (xx), s2));        \
                     s2 = fmaf(-A2, y_, B2 * (xx)); }
#define STEP_S(xx, yy) { (yy) = fmaf(B0, (xx), s1);                 \
                     s1 = fmaf(-A1, (yy), fmaf(B1, (xx), s2));      \
                     s2 = fmaf(-A2, (yy), B2 * (xx)); }

    // compute tile from wave-private LDS region, store to dst.
    // Transpose: each output chunk is written to its swizzled slot right
    // after it's produced (all cross-lane warm reads of that chunk are in
    // the warm loop, which precedes every main-loop write; LDS is in-order
    // per wave and the region is wave-private => no barrier).
#define COMPUTE_STORE(dst) do {                                          \
        float s1 = 0.0f, s2 = 0.0f;                                      \
        const int c0 = 4 * lane;                                         \
        _Pragma("unroll")                                                \
        for (int j = 0; j < 8; ++j) {          /* warm: 8 x b128 */      \
            vfloat4 v = wlds[swz(c0 + j)];                               \
            STEP_D(v.x); STEP_D(v.y); STEP_D(v.z); STEP_D(v.w);          \
        }                                                                \
        _Pragma("unroll")                                                \
        for (int j = 0; j < 4; ++j) {          /* main: 4 x b128 */      \
            vfloat4 v = wlds[swz(c0 + 8 + j)];                           \
            vfloat4 t;                                                   \
            STEP_S(v.x, t.x); STEP_S(v.y, t.y);                          \
            STEP_S(v.z, t.z); STEP_S(v.w, t.w);                          \
            wlds[swz(c0 + 8 + j)] = t;                                   \
        }                                                                \
        vfloat4* dp = (vfloat4*)(dst);                                   \
        _Pragma("unroll")                                                \
        for (int m2 = 0; m2 < 4; ++m2) {       /* coalesced nt store */  \
            vfloat4 v = wlds[swz(8 + lane + 64 * m2)];                   \
            __builtin_nontemporal_store(v, &dp[lane + 64 * m2]);         \
        }                                                                \
    } while (0)

    // --- stage tile0 ---
    if (lane < 8) wlds[lane] = ah;             // sigma=identity for c<8
    wlds[swz(  8 + lane)] = a0;
    wlds[swz( 72 + lane)] = a1;
    wlds[swz(136 + lane)] = a2;
    wlds[swz(200 + lane)] = a3;

    // --- issue tile1 loads; they fly under tile0's compute ---
    vfloat4 b0r = NTLOAD(src1 +   0 + 4 * lane);
    vfloat4 b1r = NTLOAD(src1 + 256 + 4 * lane);
    vfloat4 b2r = NTLOAD(src1 + 512 + 4 * lane);
    vfloat4 b3r = NTLOAD(src1 + 768 + 4 * lane);
    vfloat4 bh;
    if (lane < 8) {                            // tile index >=1: never zero
        bh = NTLOAD(src1 - WARM + 4 * lane);
    }

    COMPUTE_STORE(out + base0);

    // --- stage tile1 (after all tile0 LDS reads: program order) ---
    if (lane < 8) wlds[lane] = bh;
    wlds[swz(  8 + lane)] = b0r;
    wlds[swz( 72 + lane)] = b1r;
    wlds[swz(136 + lane)] = b2r;
    wlds[swz(200 + lane)] = b3r;

    COMPUTE_STORE(out + base0 + TILE);

#undef COMPUTE_STORE
#undef STEP_D
#undef STEP_S
}

extern "C" void kernel_launch(void* const* d_in, const int* in_sizes, int n_in,
                              void* d_out, int out_size, void* d_ws, size_t ws_size,
                              hipStream_t stream) {
    const float* x    = (const float*)d_in[0];
    const float* g    = (const float*)d_in[1];
    const float* R    = (const float*)d_in[2];
    const float* m_hp = (const float*)d_in[3];
    const float* m_bp = (const float*)d_in[4];
    const float* m_lp = (const float*)d_in[5];
    float* out = (float*)d_out;

    dim3 block(TPB);
    dim3 grid(BATCH * BLKS_PER_ROW);          // 2048 blocks = 8/CU, no tail
    dsvf_iir_kernel<<<grid, block, 0, stream>>>(x, g, R, m_hp, m_bp, m_lp, out);
}

// Round 8
// 116.581 us; speedup vs baseline: 1.0863x; 1.0863x over previous
//
#include <hip/hip_runtime.h>
#include <math.h>

// DSVF via exact time-domain IIR (== reference's FFT overlap-add: pole
// radius r <= 0.55 robustly; warm-up truncation 0.55^32 ~ 5e-9 relative,
// ~1e-7 absolute vs 1.6e-2 tolerance).
//
// R12 = exact R9 revert (best on record, 116.57 us).
// Cache-policy map from R10/R11 isolations:
//   {plain load, nt store} = 116.6   <- this kernel
//   {plain load, plain store} = 120.7 (nt stores worth ~4 us: output
//        stream handed to memory side as full lines, no L2 displacement)
//   {nt load, nt store} = 126.6      (nt loads cost ~10 us: read stream
//        loses L2/LLC allocation benefit)
// Structural levers all measured null: barriers (R7), LDS b32->b128+swz
// (R8), 2-tile prefetch pipeline (R9, kept as harmless). Kernel ~33 us vs
// 21.3 us traffic floor; residual attributed to launch/drain + phase
// tails, invisible to further source-level change.

#define N_PER_ROW (128 * 2048)     // 262144 samples per row
#define BATCH 64
#define TPB 256
#define OUT_BLK 16                 // outputs per thread
#define WARM 32                    // warm-up samples per thread
#define WTILE (64 * OUT_BLK)       // 1024 outputs per wave
#define TILE (TPB * OUT_BLK)       // 4096 outputs per block-tile
#define TILES_PER_ROW (N_PER_ROW / TILE)     // 64
#define TILES_PER_BLK 2
#define BLKS_PER_ROW (TILES_PER_ROW / TILES_PER_BLK)  // 32
#define WCHUNKS ((WARM + WTILE) / 4)         // 264 16-B chunks per wave

typedef float vfloat4 __attribute__((ext_vector_type(4)));

// Involution on chunk index: XOR low 3 bits with the next 3 bits.
// Every access phase lands 8 lanes per 4-bank group: conflict-free b128.
__device__ __forceinline__ int swz(int c) { return c ^ ((c >> 3) & 7); }

__global__ __launch_bounds__(256, 8) void dsvf_iir_kernel(
    const float* __restrict__ x,
    const float* __restrict__ g_p, const float* __restrict__ R_p,
    const float* __restrict__ mhp_p, const float* __restrict__ mbp_p,
    const float* __restrict__ mlp_p,
    float* __restrict__ out)
{
    __shared__ vfloat4 lds[4 * WCHUNKS];     // 4 wave-private regions, 16.9 KB

    const int p    = blockIdx.x;
    const int row  = p >> 5;                 // / BLKS_PER_ROW (=32)
    const int tl0  = (p & (BLKS_PER_ROW - 1)) * TILES_PER_BLK;
    const int k    = threadIdx.x;
    const int wid  = k >> 6;                 // wave 0..3
    const int lane = k & 63;

    const size_t base0 = (size_t)row * N_PER_ROW + (size_t)tl0 * TILE
                       + (size_t)wid * WTILE;
    const float* __restrict__ src0 = x + base0;
    const float* __restrict__ src1 = src0 + TILE;   // same wave slot, next tile
    vfloat4* const wlds = &lds[wid * WCHUNKS];

    // --- tile0 loads (registers) ---
    vfloat4 a0 = *(const vfloat4*)(src0 +   0 + 4 * lane);
    vfloat4 a1 = *(const vfloat4*)(src0 + 256 + 4 * lane);
    vfloat4 a2 = *(const vfloat4*)(src0 + 512 + 4 * lane);
    vfloat4 a3 = *(const vfloat4*)(src0 + 768 + 4 * lane);
    vfloat4 ah;
    if (lane < 8) {
        if (tl0 == 0 && wid == 0) { ah = (vfloat4){0.f, 0.f, 0.f, 0.f}; }
        else                      { ah = *(const vfloat4*)(src0 - WARM + 4 * lane); }
    }

    // --- biquad coefficients (identical math to reference, fp32) ---
    const float g = g_p[0], R = R_p[0];
    const float m_hp = mhp_p[0], m_bp = mbp_p[0], m_lp = mlp_p[0];
    const float sig = 1.0f / (1.0f + expf(-g));
    const float gt  = tanf(1.5707963267948966f * sig);   // tan(pi*sig/2)
    const float Rt  = log1pf(expf(R));                   // softplus
    const float g2  = gt * gt;
    const float b0 = g2 * m_lp + gt * m_bp + m_hp;
    const float b1 = 2.0f * g2 * m_lp - 2.0f * m_hp;
    const float b2 = g2 * m_lp - gt * m_bp + m_hp;
    const float a0c = g2 + 2.0f * Rt * gt + 1.0f;
    const float a1c = 2.0f * g2 - 2.0f;
    const float a2c = g2 - 2.0f * Rt * gt + 1.0f;
    const float inv_a0 = 1.0f / a0c;
    const float B0 = b0 * inv_a0, B1 = b1 * inv_a0, B2 = b2 * inv_a0;
    const float A1 = a1c * inv_a0, A2 = a2c * inv_a0;

#define STEP_D(xx) { float y_ = fmaf(B0, (xx), s1);                 \
                     s1 = fmaf(-A1, y_, fmaf(B1, (xx), s2));        \
                     s2 = fmaf(-A2, y_, B2 * (xx)); }
#define STEP_S(xx, yy) { (yy) = fmaf(B0, (xx), s1);                 \
                     s1 = fmaf(-A1, (yy), fmaf(B1, (xx), s2));      \
                     s2 = fmaf(-A2, (yy), B2 * (xx)); }

    // compute tile from wave-private LDS region, store to dst.
    // Transpose: each output chunk is written to its swizzled slot right
    // after it's produced (all cross-lane warm reads of that chunk are in
    // the warm loop, which precedes every main-loop write; LDS is in-order
    // per wave and the region is wave-private => no barrier).
#define COMPUTE_STORE(dst) do {                                          \
        float s1 = 0.0f, s2 = 0.0f;                                      \
        const int c0 = 4 * lane;                                         \
        _Pragma("unroll")                                                \
        for (int j = 0; j < 8; ++j) {          /* warm: 8 x b128 */      \
            vfloat4 v = wlds[swz(c0 + j)];                               \
            STEP_D(v.x); STEP_D(v.y); STEP_D(v.z); STEP_D(v.w);          \
        }                                                                \
        _Pragma("unroll")                                                \
        for (int j = 0; j < 4; ++j) {          /* main: 4 x b128 */      \
            vfloat4 v = wlds[swz(c0 + 8 + j)];                           \
            vfloat4 t;                                                   \
            STEP_S(v.x, t.x); STEP_S(v.y, t.y);                          \
            STEP_S(v.z, t.z); STEP_S(v.w, t.w);                          \
            wlds[swz(c0 + 8 + j)] = t;                                   \
        }                                                                \
        vfloat4* dp = (vfloat4*)(dst);                                   \
        _Pragma("unroll")                                                \
        for (int m2 = 0; m2 < 4; ++m2) {       /* coalesced nt store */  \
            vfloat4 v = wlds[swz(8 + lane + 64 * m2)];                   \
            __builtin_nontemporal_store(v, &dp[lane + 64 * m2]);         \
        }                                                                \
    } while (0)

    // --- stage tile0 ---
    if (lane < 8) wlds[lane] = ah;             // sigma=identity for c<8
    wlds[swz(  8 + lane)] = a0;
    wlds[swz( 72 + lane)] = a1;
    wlds[swz(136 + lane)] = a2;
    wlds[swz(200 + lane)] = a3;

    // --- issue tile1 loads; they fly under tile0's compute ---
    vfloat4 b0r = *(const vfloat4*)(src1 +   0 + 4 * lane);
    vfloat4 b1r = *(const vfloat4*)(src1 + 256 + 4 * lane);
    vfloat4 b2r = *(const vfloat4*)(src1 + 512 + 4 * lane);
    vfloat4 b3r = *(const vfloat4*)(src1 + 768 + 4 * lane);
    vfloat4 bh;
    if (lane < 8) {                            // tile index >=1: never zero
        bh = *(const vfloat4*)(src1 - WARM + 4 * lane);
    }

    COMPUTE_STORE(out + base0);

    // --- stage tile1 (after all tile0 LDS reads: program order) ---
    if (lane < 8) wlds[lane] = bh;
    wlds[swz(  8 + lane)] = b0r;
    wlds[swz( 72 + lane)] = b1r;
    wlds[swz(136 + lane)] = b2r;
    wlds[swz(200 + lane)] = b3r;

    COMPUTE_STORE(out + base0 + TILE);

#undef COMPUTE_STORE
#undef STEP_D
#undef STEP_S
}

extern "C" void kernel_launch(void* const* d_in, const int* in_sizes, int n_in,
                              void* d_out, int out_size, void* d_ws, size_t ws_size,
                              hipStream_t stream) {
    const float* x    = (const float*)d_in[0];
    const float* g    = (const float*)d_in[1];
    const float* R    = (const float*)d_in[2];
    const float* m_hp = (const float*)d_in[3];
    const float* m_bp = (const float*)d_in[4];
    const float* m_lp = (const float*)d_in[5];
    float* out = (float*)d_out;

    dim3 block(TPB);
    dim3 grid(BATCH * BLKS_PER_ROW);          // 2048 blocks = 8/CU, no tail
    dsvf_iir_kernel<<<grid, block, 0, stream>>>(x, g, R, m_hp, m_bp, m_lp, out);
}